// Round 2
// baseline (537.952 us; speedup 1.0000x reference)
//
#include <hip/hip_runtime.h>
#include <math.h>

#define EPS 1e-5f

__device__ __forceinline__ float wave_sum64(float v) {
#pragma unroll
  for (int off = 32; off >= 1; off >>= 1) v += __shfl_xor(v, off, 64);
  return v;
}

// K1: x = weather @ W_emb + b_emb + pos_encoding
__global__ __launch_bounds__(64) void k_embed(
    const float* __restrict__ weather, const float* __restrict__ coords,
    const float* __restrict__ W_emb, const float* __restrict__ b_emb,
    float* __restrict__ x) {
  int row = blockIdx.x;  // b*1024 + s
  int e = threadIdx.x;
  int b = row >> 10, s = row & 1023;
  __shared__ float wrow[32];
  if (e < 31) wrow[e] = weather[row * 31 + e];
  __syncthreads();
  float acc = b_emb[e];
#pragma unroll
  for (int i = 0; i < 31; ++i) acc = fmaf(wrow[i], W_emb[i * 64 + e], acc);
  int g = e >> 2, rem = e & 3;
  float div = __expf(-0.5756462732485115f * (float)g);
  float pe;
  if (rem == 0)      pe = sinf((float)s * div);
  else if (rem == 1) pe = cosf((float)s * div);
  else if (rem == 2) pe = sinf(coords[b * 2 + 0] * 0.017453292519943295f * div);
  else               pe = cosf(coords[b * 2 + 1] * 0.017453292519943295f * div);
  x[row * 64 + e] = acc + pe;
}

// K2: qkv = x @ W_qkv + b_qkv (+gran on q,k). 8 rows per block, thread = col.
// x rows read as broadcast float4 (L1); weights coalesced, amortized 8x.
__global__ __launch_bounds__(192) void k_qkv(
    const float* __restrict__ x, const float* __restrict__ Wq,
    const float* __restrict__ bq, const float* __restrict__ gran,
    const int* __restrict__ tidx, float* __restrict__ qkv) {
  int t = threadIdx.x;
  int row0 = blockIdx.x << 3;
  float acc[8];
  float bias = bq[t];
#pragma unroll
  for (int r = 0; r < 8; ++r) acc[r] = bias;
  const float* xp = x + (size_t)row0 * 64;
#pragma unroll 4
  for (int k4 = 0; k4 < 16; ++k4) {
    float4 xv[8];
#pragma unroll
    for (int r = 0; r < 8; ++r) xv[r] = *(const float4*)(xp + r * 64 + k4 * 4);
    float w0 = Wq[(4 * k4 + 0) * 192 + t];
    float w1 = Wq[(4 * k4 + 1) * 192 + t];
    float w2 = Wq[(4 * k4 + 2) * 192 + t];
    float w3 = Wq[(4 * k4 + 3) * 192 + t];
#pragma unroll
    for (int r = 0; r < 8; ++r) {
      acc[r] = fmaf(xv[r].x, w0, acc[r]);
      acc[r] = fmaf(xv[r].y, w1, acc[r]);
      acc[r] = fmaf(xv[r].z, w2, acc[r]);
      acc[r] = fmaf(xv[r].w, w3, acc[r]);
    }
  }
  int cq = t & 63;
  bool isqk = t < 128;
#pragma unroll
  for (int r = 0; r < 8; ++r) {
    float o = acc[r];
    if (isqk) o += gran[tidx[2 * r + 1] * 64 + cq];  // (row0+r)&7 == r
    qkv[(size_t)(row0 + r) * 192 + t] = o;
  }
}

// K3: flash attention, split-K in-block.
// bh = 8*(s%8)+h ; s2 = b*128 + s/8 ; hd = e%8.
// Block = (bh, 32-query chunk); 256 threads = 32 queries x 8 key-splits of 128.
// K/V read directly from L2 via wave-broadcast loads (no staging).
__global__ __launch_bounds__(256) void k_attn(
    const float* __restrict__ qkv, float* __restrict__ ao) {
  int bh = blockIdx.x >> 5, qc = blockIdx.x & 31;
  int slo = bh >> 3, h = bh & 7;
  int ql = threadIdx.x & 31, ks = threadIdx.x >> 5;
  int j = (qc << 5) | ql;                      // query s2
  int bq = j >> 7, sq = ((j & 127) << 3) | slo;
  const float* qb = qkv + (size_t)(((bq << 10) | sq) * 192) + (h << 3);
  float4 q0 = *(const float4*)qb;
  float4 q1 = *(const float4*)(qb + 4);
  const float scl = 0.35355339059327373f;  // 8^-0.5
  q0.x *= scl; q0.y *= scl; q0.z *= scl; q0.w *= scl;
  q1.x *= scl; q1.y *= scl; q1.z *= scl; q1.w *= scl;

  // keys r = ks*128 + i  ->  b = ks, shi = i  (128 == 2^7)
  const float* kvb = qkv + (size_t)((((ks << 10) | slo) * 192)) + (h << 3);

  float m = -1e30f, lsum = 0.f;
  float a[8];
#pragma unroll
  for (int i = 0; i < 8; ++i) a[i] = 0.f;

  for (int i = 0; i < 128; i += 4) {
    const float* r0 = kvb + (size_t)i * 1536;
    float4 ka0 = *(const float4*)(r0 + 64),        kb0 = *(const float4*)(r0 + 68);
    float4 ka1 = *(const float4*)(r0 + 1536 + 64), kb1 = *(const float4*)(r0 + 1536 + 68);
    float4 ka2 = *(const float4*)(r0 + 3072 + 64), kb2 = *(const float4*)(r0 + 3072 + 68);
    float4 ka3 = *(const float4*)(r0 + 4608 + 64), kb3 = *(const float4*)(r0 + 4608 + 68);
    float s0 = q0.x*ka0.x + q0.y*ka0.y + q0.z*ka0.z + q0.w*ka0.w
             + q1.x*kb0.x + q1.y*kb0.y + q1.z*kb0.z + q1.w*kb0.w;
    float s1 = q0.x*ka1.x + q0.y*ka1.y + q0.z*ka1.z + q0.w*ka1.w
             + q1.x*kb1.x + q1.y*kb1.y + q1.z*kb1.z + q1.w*kb1.w;
    float s2 = q0.x*ka2.x + q0.y*ka2.y + q0.z*ka2.z + q0.w*ka2.w
             + q1.x*kb2.x + q1.y*kb2.y + q1.z*kb2.z + q1.w*kb2.w;
    float s3 = q0.x*ka3.x + q0.y*ka3.y + q0.z*ka3.z + q0.w*ka3.w
             + q1.x*kb3.x + q1.y*kb3.y + q1.z*kb3.z + q1.w*kb3.w;
    float mx = fmaxf(fmaxf(s0, s1), fmaxf(s2, s3));
    float nm = fmaxf(m, mx);
    float esc = __expf(m - nm);
    float p0 = __expf(s0 - nm), p1 = __expf(s1 - nm);
    float p2 = __expf(s2 - nm), p3 = __expf(s3 - nm);
    lsum = lsum * esc + (p0 + p1) + (p2 + p3);
    float4 va0 = *(const float4*)(r0 + 128),        vb0 = *(const float4*)(r0 + 132);
    float4 va1 = *(const float4*)(r0 + 1536 + 128), vb1 = *(const float4*)(r0 + 1536 + 132);
    float4 va2 = *(const float4*)(r0 + 3072 + 128), vb2 = *(const float4*)(r0 + 3072 + 132);
    float4 va3 = *(const float4*)(r0 + 4608 + 128), vb3 = *(const float4*)(r0 + 4608 + 132);
    a[0] = fmaf(p3, va3.x, fmaf(p2, va2.x, fmaf(p1, va1.x, fmaf(p0, va0.x, a[0] * esc))));
    a[1] = fmaf(p3, va3.y, fmaf(p2, va2.y, fmaf(p1, va1.y, fmaf(p0, va0.y, a[1] * esc))));
    a[2] = fmaf(p3, va3.z, fmaf(p2, va2.z, fmaf(p1, va1.z, fmaf(p0, va0.z, a[2] * esc))));
    a[3] = fmaf(p3, va3.w, fmaf(p2, va2.w, fmaf(p1, va1.w, fmaf(p0, va0.w, a[3] * esc))));
    a[4] = fmaf(p3, vb3.x, fmaf(p2, vb2.x, fmaf(p1, vb1.x, fmaf(p0, vb0.x, a[4] * esc))));
    a[5] = fmaf(p3, vb3.y, fmaf(p2, vb2.y, fmaf(p1, vb1.y, fmaf(p0, vb0.y, a[5] * esc))));
    a[6] = fmaf(p3, vb3.z, fmaf(p2, vb2.z, fmaf(p1, vb1.z, fmaf(p0, vb0.z, a[6] * esc))));
    a[7] = fmaf(p3, vb3.w, fmaf(p2, vb2.w, fmaf(p1, vb1.w, fmaf(p0, vb0.w, a[7] * esc))));
    m = nm;
  }

  // combine 8 partials per query in LDS (stride 9 pad -> conflict-free)
  __shared__ float pm[8][32], pl[8][32], pa[8][32][9];
  pm[ks][ql] = m;
  pl[ks][ql] = lsum;
#pragma unroll
  for (int i = 0; i < 8; ++i) pa[ks][ql][i] = a[i];
  __syncthreads();
  if (threadIdx.x < 32) {
    int t = threadIdx.x;
    float M = pm[0][t];
#pragma unroll
    for (int k2 = 1; k2 < 8; ++k2) M = fmaxf(M, pm[k2][t]);
    float L = 0.f;
    float o[8];
#pragma unroll
    for (int i = 0; i < 8; ++i) o[i] = 0.f;
#pragma unroll
    for (int k2 = 0; k2 < 8; ++k2) {
      float w = __expf(pm[k2][t] - M);
      L = fmaf(pl[k2][t], w, L);
#pragma unroll
      for (int i = 0; i < 8; ++i) o[i] = fmaf(pa[k2][t][i], w, o[i]);
    }
    float inv = 1.0f / L;
    int j2 = (qc << 5) | t;
    int bq2 = j2 >> 7, sq2 = ((j2 & 127) << 3) | slo;
    float* op = ao + (size_t)((((bq2 << 10) | sq2) << 6)) + (h << 3);
    *(float4*)(op + 0) = make_float4(o[0] * inv, o[1] * inv, o[2] * inv, o[3] * inv);
    *(float4*)(op + 4) = make_float4(o[4] * inv, o[5] * inv, o[6] * inv, o[7] * inv);
  }
}

// K4: fused  x = LN2( x1 + relu(x1@W1+b1)@W2+b2 ),  x1 = LN1( x + ao@Wo+bo )
// 4 rows per block, wave = row (lane = channel). h1/x1 never touch HBM.
__global__ __launch_bounds__(256) void k_fused(
    const float* x_in, const float* __restrict__ ao,
    const float* __restrict__ Wo, const float* __restrict__ bo,
    const float* __restrict__ g1, const float* __restrict__ be1,
    const float* __restrict__ W1, const float* __restrict__ b1,
    const float* __restrict__ W2, const float* __restrict__ b2,
    const float* __restrict__ g2, const float* __restrict__ be2,
    float* x_out) {
  int t = threadIdx.x, r = t >> 6, c = t & 63;
  int row = (blockIdx.x << 2) | r;
  __shared__ float x1s[4][64];
  __shared__ float h1s[4][256];
  // ---- proj
  float acc = bo[c];
  const float* ap = ao + (size_t)row * 64;
#pragma unroll 4
  for (int k4 = 0; k4 < 16; ++k4) {
    float4 av = *(const float4*)(ap + 4 * k4);
    acc = fmaf(av.x, Wo[(4 * k4 + 0) * 64 + c], acc);
    acc = fmaf(av.y, Wo[(4 * k4 + 1) * 64 + c], acc);
    acc = fmaf(av.z, Wo[(4 * k4 + 2) * 64 + c], acc);
    acc = fmaf(av.w, Wo[(4 * k4 + 3) * 64 + c], acc);
  }
  float y = acc + x_in[(size_t)row * 64 + c];
  float s1 = wave_sum64(y), s2 = wave_sum64(y * y);
  float mean = s1 * 0.015625f, var = s2 * 0.015625f - mean * mean;
  float x1v = (y - mean) * rsqrtf(var + EPS) * g1[c] + be1[c];
  x1s[r][c] = x1v;
  __syncthreads();
  // ---- ffn1: this thread owns h1 cols 4c..4c+3
  float4 acc4 = *(const float4*)(b1 + 4 * c);
#pragma unroll 4
  for (int k4 = 0; k4 < 16; ++k4) {
    float4 xv = *(const float4*)(&x1s[r][4 * k4]);
    float4 w0 = *(const float4*)(W1 + (size_t)(4 * k4 + 0) * 256 + 4 * c);
    float4 w1 = *(const float4*)(W1 + (size_t)(4 * k4 + 1) * 256 + 4 * c);
    float4 w2 = *(const float4*)(W1 + (size_t)(4 * k4 + 2) * 256 + 4 * c);
    float4 w3 = *(const float4*)(W1 + (size_t)(4 * k4 + 3) * 256 + 4 * c);
    acc4.x = fmaf(xv.x, w0.x, acc4.x); acc4.y = fmaf(xv.x, w0.y, acc4.y);
    acc4.z = fmaf(xv.x, w0.z, acc4.z); acc4.w = fmaf(xv.x, w0.w, acc4.w);
    acc4.x = fmaf(xv.y, w1.x, acc4.x); acc4.y = fmaf(xv.y, w1.y, acc4.y);
    acc4.z = fmaf(xv.y, w1.z, acc4.z); acc4.w = fmaf(xv.y, w1.w, acc4.w);
    acc4.x = fmaf(xv.z, w2.x, acc4.x); acc4.y = fmaf(xv.z, w2.y, acc4.y);
    acc4.z = fmaf(xv.z, w2.z, acc4.z); acc4.w = fmaf(xv.z, w2.w, acc4.w);
    acc4.x = fmaf(xv.w, w3.x, acc4.x); acc4.y = fmaf(xv.w, w3.y, acc4.y);
    acc4.z = fmaf(xv.w, w3.z, acc4.z); acc4.w = fmaf(xv.w, w3.w, acc4.w);
  }
  acc4.x = fmaxf(acc4.x, 0.f); acc4.y = fmaxf(acc4.y, 0.f);
  acc4.z = fmaxf(acc4.z, 0.f); acc4.w = fmaxf(acc4.w, 0.f);
  *(float4*)(&h1s[r][4 * c]) = acc4;
  __syncthreads();
  // ---- ffn2
  float acc2 = b2[c];
#pragma unroll 4
  for (int k4 = 0; k4 < 64; ++k4) {
    float4 hv = *(const float4*)(&h1s[r][4 * k4]);
    acc2 = fmaf(hv.x, W2[(size_t)(4 * k4 + 0) * 64 + c], acc2);
    acc2 = fmaf(hv.y, W2[(size_t)(4 * k4 + 1) * 64 + c], acc2);
    acc2 = fmaf(hv.z, W2[(size_t)(4 * k4 + 2) * 64 + c], acc2);
    acc2 = fmaf(hv.w, W2[(size_t)(4 * k4 + 3) * 64 + c], acc2);
  }
  float y2 = acc2 + x1v;
  float t1 = wave_sum64(y2), t2 = wave_sum64(y2 * y2);
  float mean2 = t1 * 0.015625f, var2 = t2 * 0.015625f - mean2 * mean2;
  x_out[(size_t)row * 64 + c] =
      (y2 - mean2) * rsqrtf(var2 + EPS) * g2[c] + be2[c];
}

// K6: out = x @ W_fc + b_fc
__global__ __launch_bounds__(256) void k_head(
    const float* __restrict__ x, const float* __restrict__ Wfc,
    const float* __restrict__ bfc, float* __restrict__ out) {
  int gid = blockIdx.x * 256 + threadIdx.x;
  int r = gid >> 5, o = gid & 31;
  if (o >= 31) return;
  float acc = bfc[o];
  const float* xr = x + (size_t)r * 64;
#pragma unroll
  for (int i = 0; i < 64; ++i) acc = fmaf(xr[i], Wfc[i * 31 + o], acc);
  out[(size_t)r * 31 + o] = acc;
}

extern "C" void kernel_launch(void* const* d_in, const int* in_sizes, int n_in,
                              void* d_out, int out_size, void* d_ws, size_t ws_size,
                              hipStream_t stream) {
  const float* weather = (const float*)d_in[0];
  const float* coords  = (const float*)d_in[1];
  const int*   tidx    = (const int*)d_in[2];
  const float* W_emb   = (const float*)d_in[3];
  const float* b_emb   = (const float*)d_in[4];
  const float* W_qkv   = (const float*)d_in[5];
  const float* b_qkv   = (const float*)d_in[6];
  const float* W_out   = (const float*)d_in[7];
  const float* b_out   = (const float*)d_in[8];
  const float* gran    = (const float*)d_in[9];
  const float* g1      = (const float*)d_in[10];
  const float* be1     = (const float*)d_in[11];
  const float* W1      = (const float*)d_in[12];
  const float* b1      = (const float*)d_in[13];
  const float* W2      = (const float*)d_in[14];
  const float* b2      = (const float*)d_in[15];
  const float* g2      = (const float*)d_in[16];
  const float* be2     = (const float*)d_in[17];
  const float* W_fc    = (const float*)d_in[18];
  const float* b_fc    = (const float*)d_in[19];
  float* out = (float*)d_out;

  // workspace (floats): x | qkv | ao  = 10.5 MB
  float* x   = (float*)d_ws;
  float* qkv = x + 8192 * 64;
  float* ao  = qkv + 8192 * 192;

  k_embed<<<8192, 64, 0, stream>>>(weather, coords, W_emb, b_emb, x);
  for (int l = 0; l < 3; ++l) {
    k_qkv<<<1024, 192, 0, stream>>>(x, W_qkv + l * 64 * 192, b_qkv + l * 192,
                                    gran + l * 31 * 64, tidx, qkv);
    k_attn<<<2048, 256, 0, stream>>>(qkv, ao);
    k_fused<<<2048, 256, 0, stream>>>(x, ao, W_out + l * 64 * 64, b_out + l * 64,
                                      g1 + l * 64, be1 + l * 64,
                                      W1 + l * 64 * 256, b1 + l * 256,
                                      W2 + l * 256 * 64, b2 + l * 64,
                                      g2 + l * 64, be2 + l * 64, x);
  }
  k_head<<<1024, 256, 0, stream>>>(x, W_fc, b_fc, out);
}